// Round 2
// baseline (1555.486 us; speedup 1.0000x reference)
//
#include <hip/hip_runtime.h>
#include <cstdint>
#include <cmath>

typedef __bf16 bf16_t;
typedef __attribute__((ext_vector_type(8))) __bf16 bf16x8;
typedef __attribute__((ext_vector_type(4))) float f32x4;

#define AS_G(x) ((__attribute__((address_space(1))) void*)(x))
#define AS_L(x) ((__attribute__((address_space(3))) void*)(x))

#define BK 32

// problem constants
#define BSZ 8
#define NTOK 1024
#define CC2 512
#define KVD 1792
#define NH 4
#define FFD 2048
#define ROWS 8192  // B*N

// ---------------- GEMM core helpers (128x128 tile, 4 waves, 16x16x32 bf16 MFMA) -------------

__device__ __forceinline__ void stage_pair(const bf16_t* __restrict__ A,
                                           const bf16_t* __restrict__ B,
                                           int ld, bf16_t* ldsA, bf16_t* ldsB, int tid)
{
#pragma unroll
  for (int it = 0; it < 2; ++it) {
    int chunk = it * 256 + tid;
    int row = chunk >> 2;
    int col = (chunk & 3) << 3;
    __builtin_amdgcn_global_load_lds(AS_G(A + (long)row * ld + col),
                                     AS_L(ldsA + chunk * 8), 16, 0, 0);
    __builtin_amdgcn_global_load_lds(AS_G(B + (long)row * ld + col),
                                     AS_L(ldsB + chunk * 8), 16, 0, 0);
  }
}

__device__ __forceinline__ void mfma_step(const bf16_t* ldsA, const bf16_t* ldsB,
                                          f32x4 acc[4][4], int wr, int wc, int lane)
{
  const int quad = lane >> 4, l16 = lane & 15;
  bf16x8 a[4], b[4];
#pragma unroll
  for (int i = 0; i < 4; ++i)
    a[i] = *(const bf16x8*)(ldsA + (wr * 64 + i * 16 + l16) * BK + quad * 8);
#pragma unroll
  for (int j = 0; j < 4; ++j)
    b[j] = *(const bf16x8*)(ldsB + (wc * 64 + j * 16 + l16) * BK + quad * 8);
#pragma unroll
  for (int i = 0; i < 4; ++i)
#pragma unroll
    for (int j = 0; j < 4; ++j)
      acc[i][j] = __builtin_amdgcn_mfma_f32_16x16x32_bf16(a[i], b[j], acc[i][j], 0, 0, 0);
}

#define GEMM_PROLOG() \
  __shared__ __align__(16) bf16_t ldsA[128 * BK]; \
  __shared__ __align__(16) bf16_t ldsB[128 * BK]; \
  const int tid = threadIdx.x; \
  const int wave = tid >> 6, lane = tid & 63; \
  const int wr = wave >> 1, wc = wave & 1; \
  f32x4 acc[4][4] = {};

#define GEMM_LOOP(Aptr, Bptr, Kdim) \
  for (int k0 = 0; k0 < (Kdim); k0 += BK) { \
    stage_pair((Aptr) + k0, (Bptr) + k0, (Kdim), ldsA, ldsB, tid); \
    __syncthreads(); \
    mfma_step(ldsA, ldsB, acc, wr, wc, lane); \
    __syncthreads(); \
  }

template <typename F>
__device__ __forceinline__ void epilogue_apply(f32x4 acc[4][4], int wr, int wc, int lane, F f)
{
  const int quad = lane >> 4, l16 = lane & 15;
#pragma unroll
  for (int i = 0; i < 4; ++i)
#pragma unroll
    for (int j = 0; j < 4; ++j)
#pragma unroll
      for (int r = 0; r < 4; ++r)
        f(wr * 64 + i * 16 + quad * 4 + r, wc * 64 + j * 16 + l16, acc[i][j][r]);
}

// ---------------- small kernels -----------------------------------------------------------

__global__ void zstats_k(float* s)
{
  if (threadIdx.x < 64) s[threadIdx.x] = 0.f;
}

// transpose-convert: in f32 [R][C] -> out bf16 [C][R]
__global__ __launch_bounds__(256) void tconv_k(const float* __restrict__ in,
                                               bf16_t* __restrict__ out, int R, int Cc)
{
  __shared__ float tile[32][33];
  const int c0 = blockIdx.x * 32, r0 = blockIdx.y * 32;
  const int tx = threadIdx.x & 31, ty = threadIdx.x >> 5;
#pragma unroll
  for (int i = 0; i < 4; ++i)
    tile[ty + i * 8][tx] = in[(long)(r0 + ty + i * 8) * Cc + c0 + tx];
  __syncthreads();
#pragma unroll
  for (int i = 0; i < 4; ++i)
    out[(long)(c0 + ty + i * 8) * R + r0 + tx] = (bf16_t)tile[tx][ty + i * 8];
}

// fused LN(emb2) and LN(concat(emb1,emb2,emb3)), bf16 outputs
__global__ __launch_bounds__(256) void ln_concat_k(const float* __restrict__ e1,
                                                   const float* __restrict__ e2,
                                                   const float* __restrict__ e3,
                                                   const float* __restrict__ g1,
                                                   const float* __restrict__ b1,
                                                   const float* __restrict__ ga,
                                                   const float* __restrict__ ba,
                                                   bf16_t* __restrict__ cxln,
                                                   bf16_t* __restrict__ embln)
{
  const long row = blockIdx.x;
  const float* p1 = e1 + row * 256;
  const float* p2 = e2 + row * 512;
  const float* p3 = e3 + row * 1024;
  const int t = threadIdx.x;
  float vals[7];
  float sa = 0.f, qa = 0.f;
#pragma unroll
  for (int i = 0; i < 7; ++i) {
    int idx = t + i * 256;
    float x = (idx < 256) ? p1[idx] : (idx < 768 ? p2[idx - 256] : p3[idx - 768]);
    vals[i] = x;
    sa += x; qa += x * x;
  }
  float s2 = vals[1] + vals[2];
  float q2 = vals[1] * vals[1] + vals[2] * vals[2];
  for (int off = 32; off; off >>= 1) {
    sa += __shfl_down(sa, off, 64); qa += __shfl_down(qa, off, 64);
    s2 += __shfl_down(s2, off, 64); q2 += __shfl_down(q2, off, 64);
  }
  __shared__ float red[4][4];
  const int wave = t >> 6, lane = t & 63;
  if (lane == 0) { red[0][wave] = sa; red[1][wave] = qa; red[2][wave] = s2; red[3][wave] = q2; }
  __syncthreads();
  float SA = red[0][0] + red[0][1] + red[0][2] + red[0][3];
  float QA = red[1][0] + red[1][1] + red[1][2] + red[1][3];
  float S2 = red[2][0] + red[2][1] + red[2][2] + red[2][3];
  float Q2 = red[3][0] + red[3][1] + red[3][2] + red[3][3];
  float ma = SA * (1.f / 1792.f);
  float va = QA * (1.f / 1792.f) - ma * ma;
  float rsa = rsqrtf(va + 1e-6f);
  float m2 = S2 * (1.f / 512.f);
  float v2 = Q2 * (1.f / 512.f) - m2 * m2;
  float rs2 = rsqrtf(v2 + 1e-6f);
#pragma unroll
  for (int i = 0; i < 7; ++i) {
    int idx = t + i * 256;
    embln[row * 1792 + idx] = (bf16_t)((vals[i] - ma) * rsa * ga[idx] + ba[idx]);
  }
  cxln[row * 512 + t]       = (bf16_t)((vals[1] - m2) * rs2 * g1[t] + b1[t]);
  cxln[row * 512 + t + 256] = (bf16_t)((vals[2] - m2) * rs2 * g1[t + 256] + b1[t + 256]);
}

// plain LN over 512 (fp32 in -> bf16 out)
__global__ __launch_bounds__(256) void ln2_k(const float* __restrict__ X,
                                             const float* __restrict__ g,
                                             const float* __restrict__ bb,
                                             bf16_t* __restrict__ Y)
{
  const long row = blockIdx.x;
  const float* p = X + row * 512;
  const int t = threadIdx.x;
  float x0 = p[t], x1 = p[t + 256];
  float s = x0 + x1, q = x0 * x0 + x1 * x1;
  for (int off = 32; off; off >>= 1) {
    s += __shfl_down(s, off, 64); q += __shfl_down(q, off, 64);
  }
  __shared__ float red[2][4];
  const int wave = t >> 6, lane = t & 63;
  if (lane == 0) { red[0][wave] = s; red[1][wave] = q; }
  __syncthreads();
  float S = red[0][0] + red[0][1] + red[0][2] + red[0][3];
  float Q = red[1][0] + red[1][1] + red[1][2] + red[1][3];
  float m = S * (1.f / 512.f);
  float v = Q * (1.f / 512.f) - m * m;
  float rs = rsqrtf(v + 1e-6f);
  Y[row * 512 + t]       = (bf16_t)((x0 - m) * rs * g[t] + bb[t]);
  Y[row * 512 + t + 256] = (bf16_t)((x1 - m) * rs * g[t + 256] + bb[t + 256]);
}

// softmax over last dim (1792), with instance-norm scale (shift-invariant), in place on bf16
// one head: grid = 8*512 rows; stats has 8 (b) entries of {sum, sumsq}
__global__ __launch_bounds__(256) void softmax_k(bf16_t* __restrict__ SC,
                                                 const float* __restrict__ stats)
{
  const long rowid = blockIdx.x;          // b*512 + c
  const int b = (int)(rowid >> 9);
  const float inv_cnt = 1.f / (512.f * 1792.f);
  float m = stats[2 * b] * inv_cnt;
  float var = stats[2 * b + 1] * inv_cnt - m * m;
  float rs = rsqrtf(var + 1e-5f);
  bf16_t* rowp = SC + rowid * 1792;
  const int t = threadIdx.x;
  float v[7];
  float mx = -1e30f;
#pragma unroll
  for (int i = 0; i < 7; ++i) {
    v[i] = (float)rowp[t + i * 256] * rs;
    mx = fmaxf(mx, v[i]);
  }
  for (int off = 32; off; off >>= 1) mx = fmaxf(mx, __shfl_down(mx, off, 64));
  __shared__ float red[8];
  const int wave = t >> 6, lane = t & 63;
  if (lane == 0) red[wave] = mx;
  __syncthreads();
  mx = fmaxf(fmaxf(red[0], red[1]), fmaxf(red[2], red[3]));
  float sum = 0.f;
#pragma unroll
  for (int i = 0; i < 7; ++i) { v[i] = __expf(v[i] - mx); sum += v[i]; }
  for (int off = 32; off; off >>= 1) sum += __shfl_down(sum, off, 64);
  if (lane == 0) red[4 + wave] = sum;
  __syncthreads();
  float inv = 1.f / (red[4] + red[5] + red[6] + red[7]);
#pragma unroll
  for (int i = 0; i < 7; ++i) rowp[t + i * 256] = (bf16_t)(v[i] * inv);
}

// ---------------- GEMM kernels (single-head; blockIdx.z = batch b) -------------------------

// C[z][m][n] = sum_k W[m][k] X[z][n][k]   (weight rows x activation rows)
__global__ __launch_bounds__(256) void gemm_wx(const bf16_t* __restrict__ W,
                                               const bf16_t* __restrict__ X, long xstride,
                                               bf16_t* __restrict__ C, long cstride,
                                               int K, int ldc)
{
  const int b = blockIdx.z;
  GEMM_PROLOG();
  const bf16_t* Ap = W + (long)blockIdx.x * 128 * K;
  const bf16_t* Bp = X + b * xstride + (long)blockIdx.y * 128 * K;
  GEMM_LOOP(Ap, Bp, K);
  bf16_t* Cb = C + (long)b * cstride;
  const int rbase = blockIdx.x * 128, cbase = blockIdx.y * 128;
  epilogue_apply(acc, wr, wc, lane, [&](int rr, int cc, float v) {
    Cb[(long)(rbase + rr) * ldc + cbase + cc] = (bf16_t)v;
  });
}

// C[z][m][n] = sum_k X[z][m][k] W[n][k]
__global__ __launch_bounds__(256) void gemm_xw(const bf16_t* __restrict__ X, long xstride,
                                               const bf16_t* __restrict__ W,
                                               bf16_t* __restrict__ C, long cstride,
                                               int K, int ldc)
{
  const int b = blockIdx.z;
  GEMM_PROLOG();
  const bf16_t* Ap = X + b * xstride + (long)blockIdx.x * 128 * K;
  const bf16_t* Bp = W + (long)blockIdx.y * 128 * K;
  GEMM_LOOP(Ap, Bp, K);
  bf16_t* Cb = C + (long)b * cstride;
  const int rbase = blockIdx.x * 128, cbase = blockIdx.y * 128;
  epilogue_apply(acc, wr, wc, lane, [&](int rr, int cc, float v) {
    Cb[(long)(rbase + rr) * ldc + cbase + cc] = (bf16_t)v;
  });
}

// scores: SC[b][c][k] = sum_n QT[b][c][n] KT[b][k][n] / sqrt(KV); + per-b sum/sumsq stats
__global__ __launch_bounds__(256) void gemm_scores(const bf16_t* __restrict__ QT,
                                                   const bf16_t* __restrict__ KT,
                                                   bf16_t* __restrict__ SC,
                                                   float* __restrict__ stats)
{
  const int b = blockIdx.z;
  GEMM_PROLOG();
  const bf16_t* Ap = QT + (long)b * CC2 * NTOK + (long)blockIdx.x * 128 * NTOK;
  const bf16_t* Bp = KT + (long)b * KVD * NTOK + (long)blockIdx.y * 128 * NTOK;
  GEMM_LOOP(Ap, Bp, NTOK);
  const float scale = 0.02362277854f;  // 1/sqrt(1792)
  bf16_t* Cb = SC + (long)b * CC2 * KVD;
  const int rbase = blockIdx.x * 128, cbase = blockIdx.y * 128;
  float s = 0.f, q = 0.f;
  epilogue_apply(acc, wr, wc, lane, [&](int rr, int cc, float v) {
    v *= scale;
    Cb[(long)(rbase + rr) * KVD + cbase + cc] = (bf16_t)v;
    s += v; q += v * v;
  });
  for (int off = 32; off; off >>= 1) { s += __shfl_down(s, off, 64); q += __shfl_down(q, off, 64); }
  __shared__ float red[8];
  if (lane == 0) { red[wave] = s; red[4 + wave] = q; }
  __syncthreads();
  if (tid == 0) {
    atomicAdd(&stats[2 * b],     red[0] + red[1] + red[2] + red[3]);
    atomicAdd(&stats[2 * b + 1], red[4] + red[5] + red[6] + red[7]);
  }
}

// ctx accumulate over heads: CTX[b][n][c] (+)= 1/4 sum_k V[b][n][k] * P[b][c][k]; bf16
__global__ __launch_bounds__(256) void gemm_ctx(const bf16_t* __restrict__ V,
                                                const bf16_t* __restrict__ P,
                                                bf16_t* __restrict__ CTX, int first)
{
  const int b = blockIdx.z;
  GEMM_PROLOG();
  const bf16_t* Ap = V + (long)b * NTOK * KVD + (long)blockIdx.x * 128 * KVD;
  const bf16_t* Bp = P + (long)b * CC2 * KVD + (long)blockIdx.y * 128 * KVD;
  GEMM_LOOP(Ap, Bp, KVD);
  bf16_t* Cb = CTX + (long)b * NTOK * CC2;
  const int rbase = blockIdx.x * 128, cbase = blockIdx.y * 128;
  epilogue_apply(acc, wr, wc, lane, [&](int rr, int cc, float v) {
    long idx = (long)(rbase + rr) * CC2 + cbase + cc;
    float prev = first ? 0.f : (float)Cb[idx];
    Cb[idx] = (bf16_t)(prev + v * 0.25f);
  });
}

// o-proj + residual: CX2 = CTX@WOT^T + emb2 (fp32 out)
__global__ __launch_bounds__(256) void gemm_resid(const bf16_t* __restrict__ A,
                                                  const bf16_t* __restrict__ B,
                                                  const float* __restrict__ emb2,
                                                  float* __restrict__ CX2)
{
  GEMM_PROLOG();
  const bf16_t* Ap = A + (long)blockIdx.x * 128 * CC2;
  const bf16_t* Bp = B + (long)blockIdx.y * 128 * CC2;
  GEMM_LOOP(Ap, Bp, CC2);
  const int rbase = blockIdx.x * 128, cbase = blockIdx.y * 128;
  epilogue_apply(acc, wr, wc, lane, [&](int rr, int cc, float v) {
    long idx = (long)(rbase + rr) * CC2 + cbase + cc;
    CX2[idx] = v + emb2[idx];
  });
}

// fc1 + bias + exact gelu -> bf16
__global__ __launch_bounds__(256) void gemm_gelu(const bf16_t* __restrict__ A,
                                                 const bf16_t* __restrict__ B,
                                                 const float* __restrict__ bias,
                                                 bf16_t* __restrict__ H)
{
  GEMM_PROLOG();
  const bf16_t* Ap = A + (long)blockIdx.x * 128 * CC2;
  const bf16_t* Bp = B + (long)blockIdx.y * 128 * CC2;
  GEMM_LOOP(Ap, Bp, CC2);
  const int rbase = blockIdx.x * 128, cbase = blockIdx.y * 128;
  epilogue_apply(acc, wr, wc, lane, [&](int rr, int cc, float v) {
    float x = v + bias[cbase + cc];
    float g = 0.5f * x * (1.0f + erff(x * 0.70710678118f));
    H[(long)(rbase + rr) * FFD + cbase + cc] = (bf16_t)g;
  });
}

// fc2 + bias + residual -> fp32 out
__global__ __launch_bounds__(256) void gemm_out(const bf16_t* __restrict__ A,
                                                const bf16_t* __restrict__ B,
                                                const float* __restrict__ bias,
                                                const float* __restrict__ CX2,
                                                float* __restrict__ OUT)
{
  GEMM_PROLOG();
  const bf16_t* Ap = A + (long)blockIdx.x * 128 * FFD;
  const bf16_t* Bp = B + (long)blockIdx.y * 128 * FFD;
  GEMM_LOOP(Ap, Bp, FFD);
  const int rbase = blockIdx.x * 128, cbase = blockIdx.y * 128;
  epilogue_apply(acc, wr, wc, lane, [&](int rr, int cc, float v) {
    long idx = (long)(rbase + rr) * CC2 + cbase + cc;
    OUT[idx] = v + bias[cbase + cc] + CX2[idx];
  });
}

// ---------------- host launcher -----------------------------------------------------------

extern "C" void kernel_launch(void* const* d_in, const int* in_sizes, int n_in,
                              void* d_out, int out_size, void* d_ws, size_t ws_size,
                              hipStream_t stream)
{
  const float* emb1   = (const float*)d_in[0];
  const float* emb2   = (const float*)d_in[1];
  const float* emb3   = (const float*)d_in[2];
  const float* Wq     = (const float*)d_in[3];
  const float* Wk     = (const float*)d_in[4];
  const float* Wv     = (const float*)d_in[5];
  const float* Wout   = (const float*)d_in[6];
  const float* ln1_g  = (const float*)d_in[7];
  const float* ln1_b  = (const float*)d_in[8];
  const float* lnall_g = (const float*)d_in[9];
  const float* lnall_b = (const float*)d_in[10];
  const float* lnffn_g = (const float*)d_in[11];
  const float* lnffn_b = (const float*)d_in[12];
  const float* fc1_w  = (const float*)d_in[13];
  const float* fc1_b  = (const float*)d_in[14];
  const float* fc2_w  = (const float*)d_in[15];
  const float* fc2_b  = (const float*)d_in[16];
  float* out = (float*)d_out;

  char* ws = (char*)d_ws;
  size_t off = 0;
  auto alloc = [&](size_t bytes) {
    size_t r = off;
    off = (off + bytes + 255) & ~(size_t)255;
    return r;
  };

  // persistent buffers (~66 MB)
  size_t oCXLN  = alloc((size_t)ROWS * CC2 * 2);       // 8.4 MB; aliased by X2LN post-attention
  size_t oEMBLN = alloc((size_t)ROWS * KVD * 2);       // 29.4 MB
  size_t oCTX   = alloc((size_t)ROWS * CC2 * 2);       // 8.4 MB bf16 head-accumulated
  size_t oCX2   = alloc((size_t)ROWS * CC2 * 4);       // 16.8 MB fp32
  size_t oWOT   = alloc((size_t)CC2 * CC2 * 2);
  size_t oF1T   = alloc((size_t)FFD * CC2 * 2);
  size_t oF2T   = alloc((size_t)CC2 * FFD * 2);
  size_t oSTATS = alloc(64 * 4);
  // per-head scratch region (~66 MB), reused each head; FFN hidden (33.5 MB) aliases it
  size_t oSCR   = alloc(0);
  size_t oWQTh  = alloc((size_t)CC2 * CC2 * 2);        // 0.5 MB
  size_t oWKTh  = alloc((size_t)KVD * KVD * 2);        // 6.4 MB
  size_t oWVTh  = alloc((size_t)KVD * KVD * 2);        // 6.4 MB
  size_t oQTh   = alloc((size_t)BSZ * CC2 * NTOK * 2); // 8.4 MB
  size_t oKTh   = alloc((size_t)BSZ * KVD * NTOK * 2); // 29.4 MB (V aliases)
  size_t oSCh   = alloc((size_t)BSZ * CC2 * KVD * 2);  // 14.7 MB
  (void)ws_size; (void)in_sizes; (void)n_in; (void)out_size;

  bf16_t* CXLN  = (bf16_t*)(ws + oCXLN);
  bf16_t* EMBLN = (bf16_t*)(ws + oEMBLN);
  bf16_t* CTX   = (bf16_t*)(ws + oCTX);
  float*  CX2   = (float*)(ws + oCX2);
  bf16_t* WOT   = (bf16_t*)(ws + oWOT);
  bf16_t* F1T   = (bf16_t*)(ws + oF1T);
  bf16_t* F2T   = (bf16_t*)(ws + oF2T);
  float*  STATS = (float*)(ws + oSTATS);
  bf16_t* WQTh  = (bf16_t*)(ws + oWQTh);
  bf16_t* WKTh  = (bf16_t*)(ws + oWKTh);
  bf16_t* WVTh  = (bf16_t*)(ws + oWVTh);
  bf16_t* QTh   = (bf16_t*)(ws + oQTh);
  bf16_t* KTh   = (bf16_t*)(ws + oKTh);
  bf16_t* Vh    = KTh;                  // v overwrites kT after softmax
  bf16_t* SCh   = (bf16_t*)(ws + oSCh);
  bf16_t* FFNH  = (bf16_t*)(ws + oSCR); // FFN hidden aliases per-head scratch
  bf16_t* X2LN  = CXLN;                 // ffn-LN aliases cxln after attention

  // stats zero + global weight transpose-converts
  zstats_k<<<1, 64, 0, stream>>>(STATS);
  tconv_k<<<dim3(16, 16), 256, 0, stream>>>(Wout, WOT, 512, 512);
  tconv_k<<<dim3(64, 16), 256, 0, stream>>>(fc1_w, F1T, 512, 2048);
  tconv_k<<<dim3(16, 64), 256, 0, stream>>>(fc2_w, F2T, 2048, 512);

  // fused layernorms -> bf16 activations
  ln_concat_k<<<8192, 256, 0, stream>>>(emb1, emb2, emb3, ln1_g, ln1_b,
                                        lnall_g, lnall_b, CXLN, EMBLN);

  // attention: loop over heads, reusing the scratch region
  for (int h = 0; h < NH; ++h) {
    tconv_k<<<dim3(16, 16), 256, 0, stream>>>(Wq + (long)h * 512 * 512, WQTh, 512, 512);
    tconv_k<<<dim3(56, 56), 256, 0, stream>>>(Wk + (long)h * 1792 * 1792, WKTh, 1792, 1792);
    tconv_k<<<dim3(56, 56), 256, 0, stream>>>(Wv + (long)h * 1792 * 1792, WVTh, 1792, 1792);

    // qT[b][d][n], kT[b][k][n] (token-minor so scores GEMM needs no transpose)
    gemm_wx<<<dim3(4, 8, 8), 256, 0, stream>>>(WQTh, CXLN, (long)NTOK * CC2,
                                               QTh, (long)CC2 * NTOK, CC2, NTOK);
    gemm_wx<<<dim3(14, 8, 8), 256, 0, stream>>>(WKTh, EMBLN, (long)NTOK * KVD,
                                                KTh, (long)KVD * NTOK, KVD, NTOK);

    // scores + instance-norm stats; softmax (shift-invariant => only scale matters)
    gemm_scores<<<dim3(4, 14, 8), 256, 0, stream>>>(QTh, KTh, SCh, STATS + h * 16);
    softmax_k<<<4096, 256, 0, stream>>>(SCh, STATS + h * 16);

    // v[b][n][k] (over kT's storage), ctx accumulation
    gemm_xw<<<dim3(8, 14, 8), 256, 0, stream>>>(EMBLN, (long)NTOK * KVD, WVTh,
                                                Vh, (long)NTOK * KVD, KVD, KVD);
    gemm_ctx<<<dim3(8, 4, 8), 256, 0, stream>>>(Vh, SCh, CTX, h == 0 ? 1 : 0);
  }

  // o-proj + residual
  gemm_resid<<<dim3(64, 4), 256, 0, stream>>>(CTX, WOT, emb2, CX2);

  // FFN
  ln2_k<<<8192, 256, 0, stream>>>(CX2, lnffn_g, lnffn_b, X2LN);
  gemm_gelu<<<dim3(64, 16), 256, 0, stream>>>(X2LN, F1T, fc1_b, FFNH);
  gemm_out<<<dim3(64, 4), 256, 0, stream>>>(FFNH, F2T, fc2_b, CX2, out);
}

// Round 3
// 946.446 us; speedup vs baseline: 1.6435x; 1.6435x over previous
//
#include <hip/hip_runtime.h>
#include <cstdint>
#include <cmath>

typedef __bf16 bf16_t;
typedef __attribute__((ext_vector_type(8))) __bf16 bf16x8;
typedef __attribute__((ext_vector_type(4))) float f32x4;

#define AS_G(x) ((__attribute__((address_space(1))) void*)(x))
#define AS_L(x) ((__attribute__((address_space(3))) void*)(x))

#define BK 32

// problem constants
#define BSZ 8
#define NTOK 1024
#define CC2 512
#define KVD 1792
#define NH 4
#define FFD 2048
#define ROWS 8192  // B*N

// ---------------- GEMM core helpers (128x128 tile, 4 waves, 16x16x32 bf16 MFMA) -------------

__device__ __forceinline__ void stage_pair(const bf16_t* __restrict__ A,
                                           const bf16_t* __restrict__ B,
                                           int ld, bf16_t* ldsA, bf16_t* ldsB, int tid)
{
#pragma unroll
  for (int it = 0; it < 2; ++it) {
    int chunk = it * 256 + tid;
    int row = chunk >> 2;
    int col = (chunk & 3) << 3;
    __builtin_amdgcn_global_load_lds(AS_G(A + (long)row * ld + col),
                                     AS_L(ldsA + chunk * 8), 16, 0, 0);
    __builtin_amdgcn_global_load_lds(AS_G(B + (long)row * ld + col),
                                     AS_L(ldsB + chunk * 8), 16, 0, 0);
  }
}

__device__ __forceinline__ void mfma_step(const bf16_t* ldsA, const bf16_t* ldsB,
                                          f32x4 acc[4][4], int wr, int wc, int lane)
{
  const int quad = lane >> 4, l16 = lane & 15;
  bf16x8 a[4], b[4];
#pragma unroll
  for (int i = 0; i < 4; ++i)
    a[i] = *(const bf16x8*)(ldsA + (wr * 64 + i * 16 + l16) * BK + quad * 8);
#pragma unroll
  for (int j = 0; j < 4; ++j)
    b[j] = *(const bf16x8*)(ldsB + (wc * 64 + j * 16 + l16) * BK + quad * 8);
#pragma unroll
  for (int i = 0; i < 4; ++i)
#pragma unroll
    for (int j = 0; j < 4; ++j)
      acc[i][j] = __builtin_amdgcn_mfma_f32_16x16x32_bf16(a[i], b[j], acc[i][j], 0, 0, 0);
}

#define GEMM_PROLOG() \
  __shared__ __align__(16) bf16_t ldsA[128 * BK]; \
  __shared__ __align__(16) bf16_t ldsB[128 * BK]; \
  const int tid = threadIdx.x; \
  const int wave = tid >> 6, lane = tid & 63; \
  const int wr = wave >> 1, wc = wave & 1; \
  f32x4 acc[4][4] = {};

#define GEMM_LOOP(Aptr, Bptr, Kdim) \
  for (int k0 = 0; k0 < (Kdim); k0 += BK) { \
    stage_pair((Aptr) + k0, (Bptr) + k0, (Kdim), ldsA, ldsB, tid); \
    __syncthreads(); \
    mfma_step(ldsA, ldsB, acc, wr, wc, lane); \
    __syncthreads(); \
  }

template <typename F>
__device__ __forceinline__ void epilogue_apply(f32x4 acc[4][4], int wr, int wc, int lane, F f)
{
  const int quad = lane >> 4, l16 = lane & 15;
#pragma unroll
  for (int i = 0; i < 4; ++i)
#pragma unroll
    for (int j = 0; j < 4; ++j)
#pragma unroll
      for (int r = 0; r < 4; ++r)
        f(wr * 64 + i * 16 + quad * 4 + r, wc * 64 + j * 16 + l16, acc[i][j][r]);
}

// ---------------- small kernels -----------------------------------------------------------

__global__ void zstats_k(float* s)
{
  if (threadIdx.x < 64) s[threadIdx.x] = 0.f;
}

// transpose-convert: in f32 [Z][R][C] -> out bf16 [Z][C][R]
__global__ __launch_bounds__(256) void tconv_k(const float* __restrict__ in,
                                               bf16_t* __restrict__ out, int R, int Cc)
{
  __shared__ float tile[32][33];
  const long base = (long)blockIdx.z * R * Cc;
  const int c0 = blockIdx.x * 32, r0 = blockIdx.y * 32;
  const int tx = threadIdx.x & 31, ty = threadIdx.x >> 5;
#pragma unroll
  for (int i = 0; i < 4; ++i)
    tile[ty + i * 8][tx] = in[base + (long)(r0 + ty + i * 8) * Cc + c0 + tx];
  __syncthreads();
#pragma unroll
  for (int i = 0; i < 4; ++i)
    out[base + (long)(c0 + ty + i * 8) * R + r0 + tx] = (bf16_t)tile[tx][ty + i * 8];
}

// transpose bf16 [Z][R][C] -> bf16 [Z][C][R]
__global__ __launch_bounds__(256) void tconv_bf_k(const bf16_t* __restrict__ in,
                                                  bf16_t* __restrict__ out, int R, int Cc)
{
  __shared__ float tile[32][33];
  const long base = (long)blockIdx.z * R * Cc;
  const int c0 = blockIdx.x * 32, r0 = blockIdx.y * 32;
  const int tx = threadIdx.x & 31, ty = threadIdx.x >> 5;
#pragma unroll
  for (int i = 0; i < 4; ++i)
    tile[ty + i * 8][tx] = (float)in[base + (long)(r0 + ty + i * 8) * Cc + c0 + tx];
  __syncthreads();
#pragma unroll
  for (int i = 0; i < 4; ++i)
    out[base + (long)(c0 + ty + i * 8) * R + r0 + tx] = (bf16_t)tile[tx][ty + i * 8];
}

// f32 -> bf16 cast (no transpose), n multiple of 1024
__global__ __launch_bounds__(256) void cast_k(const float* __restrict__ in,
                                              bf16_t* __restrict__ out, long n)
{
  long i = ((long)blockIdx.x * 256 + threadIdx.x) * 4;
  if (i + 3 < n) {
    float4 v = *(const float4*)(in + i);
    out[i] = (bf16_t)v.x; out[i + 1] = (bf16_t)v.y;
    out[i + 2] = (bf16_t)v.z; out[i + 3] = (bf16_t)v.w;
  }
}

// fused LN(emb2) and LN(concat(emb1,emb2,emb3)), bf16 outputs
__global__ __launch_bounds__(256) void ln_concat_k(const float* __restrict__ e1,
                                                   const float* __restrict__ e2,
                                                   const float* __restrict__ e3,
                                                   const float* __restrict__ g1,
                                                   const float* __restrict__ b1,
                                                   const float* __restrict__ ga,
                                                   const float* __restrict__ ba,
                                                   bf16_t* __restrict__ cxln,
                                                   bf16_t* __restrict__ embln)
{
  const long row = blockIdx.x;
  const float* p1 = e1 + row * 256;
  const float* p2 = e2 + row * 512;
  const float* p3 = e3 + row * 1024;
  const int t = threadIdx.x;
  float vals[7];
  float sa = 0.f, qa = 0.f;
#pragma unroll
  for (int i = 0; i < 7; ++i) {
    int idx = t + i * 256;
    float x = (idx < 256) ? p1[idx] : (idx < 768 ? p2[idx - 256] : p3[idx - 768]);
    vals[i] = x;
    sa += x; qa += x * x;
  }
  float s2 = vals[1] + vals[2];
  float q2 = vals[1] * vals[1] + vals[2] * vals[2];
  for (int off = 32; off; off >>= 1) {
    sa += __shfl_down(sa, off, 64); qa += __shfl_down(qa, off, 64);
    s2 += __shfl_down(s2, off, 64); q2 += __shfl_down(q2, off, 64);
  }
  __shared__ float red[4][4];
  const int wave = t >> 6, lane = t & 63;
  if (lane == 0) { red[0][wave] = sa; red[1][wave] = qa; red[2][wave] = s2; red[3][wave] = q2; }
  __syncthreads();
  float SA = red[0][0] + red[0][1] + red[0][2] + red[0][3];
  float QA = red[1][0] + red[1][1] + red[1][2] + red[1][3];
  float S2 = red[2][0] + red[2][1] + red[2][2] + red[2][3];
  float Q2 = red[3][0] + red[3][1] + red[3][2] + red[3][3];
  float ma = SA * (1.f / 1792.f);
  float va = QA * (1.f / 1792.f) - ma * ma;
  float rsa = rsqrtf(va + 1e-6f);
  float m2 = S2 * (1.f / 512.f);
  float v2 = Q2 * (1.f / 512.f) - m2 * m2;
  float rs2 = rsqrtf(v2 + 1e-6f);
#pragma unroll
  for (int i = 0; i < 7; ++i) {
    int idx = t + i * 256;
    embln[row * 1792 + idx] = (bf16_t)((vals[i] - ma) * rsa * ga[idx] + ba[idx]);
  }
  cxln[row * 512 + t]       = (bf16_t)((vals[1] - m2) * rs2 * g1[t] + b1[t]);
  cxln[row * 512 + t + 256] = (bf16_t)((vals[2] - m2) * rs2 * g1[t + 256] + b1[t + 256]);
}

// plain LN over 512 (fp32 in -> bf16 out)
__global__ __launch_bounds__(256) void ln2_k(const float* __restrict__ X,
                                             const float* __restrict__ g,
                                             const float* __restrict__ bb,
                                             bf16_t* __restrict__ Y)
{
  const long row = blockIdx.x;
  const float* p = X + row * 512;
  const int t = threadIdx.x;
  float x0 = p[t], x1 = p[t + 256];
  float s = x0 + x1, q = x0 * x0 + x1 * x1;
  for (int off = 32; off; off >>= 1) {
    s += __shfl_down(s, off, 64); q += __shfl_down(q, off, 64);
  }
  __shared__ float red[2][4];
  const int wave = t >> 6, lane = t & 63;
  if (lane == 0) { red[0][wave] = s; red[1][wave] = q; }
  __syncthreads();
  float S = red[0][0] + red[0][1] + red[0][2] + red[0][3];
  float Q = red[1][0] + red[1][1] + red[1][2] + red[1][3];
  float m = S * (1.f / 512.f);
  float v = Q * (1.f / 512.f) - m * m;
  float rs = rsqrtf(v + 1e-6f);
  Y[row * 512 + t]       = (bf16_t)((x0 - m) * rs * g[t] + bb[t]);
  Y[row * 512 + t + 256] = (bf16_t)((x1 - m) * rs * g[t + 256] + bb[t + 256]);
}

// softmax over last dim (1792), with instance-norm scale (shift-invariant), in place on bf16
// one head: grid = 8*512 rows; stats has 8 (b) entries of {sum, sumsq}
__global__ __launch_bounds__(256) void softmax_k(bf16_t* __restrict__ SC,
                                                 const float* __restrict__ stats)
{
  const long rowid = blockIdx.x;          // b*512 + c
  const int b = (int)(rowid >> 9);
  const float inv_cnt = 1.f / (512.f * 1792.f);
  float m = stats[2 * b] * inv_cnt;
  float var = stats[2 * b + 1] * inv_cnt - m * m;
  float rs = rsqrtf(var + 1e-5f);
  bf16_t* rowp = SC + rowid * 1792;
  const int t = threadIdx.x;
  float v[7];
  float mx = -1e30f;
#pragma unroll
  for (int i = 0; i < 7; ++i) {
    v[i] = (float)rowp[t + i * 256] * rs;
    mx = fmaxf(mx, v[i]);
  }
  for (int off = 32; off; off >>= 1) mx = fmaxf(mx, __shfl_down(mx, off, 64));
  __shared__ float red[8];
  const int wave = t >> 6, lane = t & 63;
  if (lane == 0) red[wave] = mx;
  __syncthreads();
  mx = fmaxf(fmaxf(red[0], red[1]), fmaxf(red[2], red[3]));
  float sum = 0.f;
#pragma unroll
  for (int i = 0; i < 7; ++i) { v[i] = __expf(v[i] - mx); sum += v[i]; }
  for (int off = 32; off; off >>= 1) sum += __shfl_down(sum, off, 64);
  if (lane == 0) red[4 + wave] = sum;
  __syncthreads();
  float inv = 1.f / (red[4] + red[5] + red[6] + red[7]);
#pragma unroll
  for (int i = 0; i < 7; ++i) rowp[t + i * 256] = (bf16_t)(v[i] * inv);
}

// ---------------- GEMM kernels (nt-core; blockIdx.z = batch b) -----------------------------

// generic: C[z][m][n] = sum_k A[z][m][k] B[z][n][k] (stride 0 = shared operand)
__global__ __launch_bounds__(256) void gemm_ab(const bf16_t* __restrict__ A, long astride,
                                               const bf16_t* __restrict__ B, long bstride,
                                               bf16_t* __restrict__ C, long cstride,
                                               int K, int ldc)
{
  const int z = blockIdx.z;
  GEMM_PROLOG();
  const bf16_t* Ap = A + z * astride + (long)blockIdx.x * 128 * K;
  const bf16_t* Bp = B + z * bstride + (long)blockIdx.y * 128 * K;
  GEMM_LOOP(Ap, Bp, K);
  bf16_t* Cb = C + (long)z * cstride;
  const int rbase = blockIdx.x * 128, cbase = blockIdx.y * 128;
  epilogue_apply(acc, wr, wc, lane, [&](int rr, int cc, float v) {
    Cb[(long)(rbase + rr) * ldc + cbase + cc] = (bf16_t)v;
  });
}

// scores: SC[b][c2][d] = sum_c T1[b][c2][c] WkT[d][c] / sqrt(KV); + per-b sum/sumsq stats
__global__ __launch_bounds__(256) void gemm_scores(const bf16_t* __restrict__ T1,
                                                   const bf16_t* __restrict__ WkT,
                                                   bf16_t* __restrict__ SC,
                                                   float* __restrict__ stats)
{
  const int b = blockIdx.z;
  GEMM_PROLOG();
  const bf16_t* Ap = T1 + (long)b * CC2 * KVD + (long)blockIdx.x * 128 * KVD;
  const bf16_t* Bp = WkT + (long)blockIdx.y * 128 * KVD;
  GEMM_LOOP(Ap, Bp, KVD);
  const float scale = 0.02362277854f;  // 1/sqrt(1792)
  bf16_t* Cb = SC + (long)b * CC2 * KVD;
  const int rbase = blockIdx.x * 128, cbase = blockIdx.y * 128;
  float s = 0.f, q = 0.f;
  epilogue_apply(acc, wr, wc, lane, [&](int rr, int cc, float v) {
    v *= scale;
    Cb[(long)(rbase + rr) * KVD + cbase + cc] = (bf16_t)v;
    s += v; q += v * v;
  });
  for (int off = 32; off; off >>= 1) { s += __shfl_down(s, off, 64); q += __shfl_down(q, off, 64); }
  __shared__ float red[8];
  if (lane == 0) { red[wave] = s; red[4 + wave] = q; }
  __syncthreads();
  if (tid == 0) {
    atomicAdd(&stats[2 * b],     red[0] + red[1] + red[2] + red[3]);
    atomicAdd(&stats[2 * b + 1], red[4] + red[5] + red[6] + red[7]);
  }
}

// M accumulate over heads: Msum[b][c2][c] (+)= 0.25 * sum_d P[b][c2][d] WvB[c][d]
__global__ __launch_bounds__(256) void gemm_macc(const bf16_t* __restrict__ P,
                                                 const bf16_t* __restrict__ WvB,
                                                 bf16_t* __restrict__ M, int first)
{
  const int b = blockIdx.z;
  GEMM_PROLOG();
  const bf16_t* Ap = P + (long)b * CC2 * KVD + (long)blockIdx.x * 128 * KVD;
  const bf16_t* Bp = WvB + (long)blockIdx.y * 128 * KVD;
  GEMM_LOOP(Ap, Bp, KVD);
  bf16_t* Cb = M + (long)b * CC2 * KVD;
  const int rbase = blockIdx.x * 128, cbase = blockIdx.y * 128;
  epilogue_apply(acc, wr, wc, lane, [&](int rr, int cc, float v) {
    long idx = (long)(rbase + rr) * KVD + cbase + cc;
    float prev = first ? 0.f : (float)Cb[idx];
    Cb[idx] = (bf16_t)(prev + v * 0.25f);
  });
}

// o-proj + residual: CX2 = CTX@WOT^T + emb2 (fp32 out)
__global__ __launch_bounds__(256) void gemm_resid(const bf16_t* __restrict__ A,
                                                  const bf16_t* __restrict__ B,
                                                  const float* __restrict__ emb2,
                                                  float* __restrict__ CX2)
{
  GEMM_PROLOG();
  const bf16_t* Ap = A + (long)blockIdx.x * 128 * CC2;
  const bf16_t* Bp = B + (long)blockIdx.y * 128 * CC2;
  GEMM_LOOP(Ap, Bp, CC2);
  const int rbase = blockIdx.x * 128, cbase = blockIdx.y * 128;
  epilogue_apply(acc, wr, wc, lane, [&](int rr, int cc, float v) {
    long idx = (long)(rbase + rr) * CC2 + cbase + cc;
    CX2[idx] = v + emb2[idx];
  });
}

// fc1 + bias + exact gelu -> bf16
__global__ __launch_bounds__(256) void gemm_gelu(const bf16_t* __restrict__ A,
                                                 const bf16_t* __restrict__ B,
                                                 const float* __restrict__ bias,
                                                 bf16_t* __restrict__ H)
{
  GEMM_PROLOG();
  const bf16_t* Ap = A + (long)blockIdx.x * 128 * CC2;
  const bf16_t* Bp = B + (long)blockIdx.y * 128 * CC2;
  GEMM_LOOP(Ap, Bp, CC2);
  const int rbase = blockIdx.x * 128, cbase = blockIdx.y * 128;
  epilogue_apply(acc, wr, wc, lane, [&](int rr, int cc, float v) {
    float x = v + bias[cbase + cc];
    float g = 0.5f * x * (1.0f + erff(x * 0.70710678118f));
    H[(long)(rbase + rr) * FFD + cbase + cc] = (bf16_t)g;
  });
}

// fc2 + bias + residual -> fp32 out
__global__ __launch_bounds__(256) void gemm_out(const bf16_t* __restrict__ A,
                                                const bf16_t* __restrict__ B,
                                                const float* __restrict__ bias,
                                                const float* __restrict__ CX2,
                                                float* __restrict__ OUT)
{
  GEMM_PROLOG();
  const bf16_t* Ap = A + (long)blockIdx.x * 128 * FFD;
  const bf16_t* Bp = B + (long)blockIdx.y * 128 * FFD;
  GEMM_LOOP(Ap, Bp, FFD);
  const int rbase = blockIdx.x * 128, cbase = blockIdx.y * 128;
  epilogue_apply(acc, wr, wc, lane, [&](int rr, int cc, float v) {
    long idx = (long)(rbase + rr) * CC2 + cbase + cc;
    OUT[idx] = v + bias[cbase + cc] + CX2[idx];
  });
}

// ---------------- host launcher -----------------------------------------------------------

extern "C" void kernel_launch(void* const* d_in, const int* in_sizes, int n_in,
                              void* d_out, int out_size, void* d_ws, size_t ws_size,
                              hipStream_t stream)
{
  const float* emb1   = (const float*)d_in[0];
  const float* emb2   = (const float*)d_in[1];
  const float* emb3   = (const float*)d_in[2];
  const float* Wq     = (const float*)d_in[3];
  const float* Wk     = (const float*)d_in[4];
  const float* Wv     = (const float*)d_in[5];
  const float* Wout   = (const float*)d_in[6];
  const float* ln1_g  = (const float*)d_in[7];
  const float* ln1_b  = (const float*)d_in[8];
  const float* lnall_g = (const float*)d_in[9];
  const float* lnall_b = (const float*)d_in[10];
  const float* lnffn_g = (const float*)d_in[11];
  const float* lnffn_b = (const float*)d_in[12];
  const float* fc1_w  = (const float*)d_in[13];
  const float* fc1_b  = (const float*)d_in[14];
  const float* fc2_w  = (const float*)d_in[15];
  const float* fc2_b  = (const float*)d_in[16];
  float* out = (float*)d_out;

  char* ws = (char*)d_ws;
  size_t off = 0;
  auto alloc = [&](size_t bytes) {
    size_t r = off;
    off = (off + bytes + 255) & ~(size_t)255;
    return r;
  };

  // persistent buffers
  size_t oEMBLN = alloc((size_t)ROWS * KVD * 2);        // 29.4 MB (until ctx GEMM)
  size_t oCXLN  = alloc((size_t)ROWS * CC2 * 2);        // 8.4 MB; X2LN aliases later
  size_t oCX2   = alloc((size_t)ROWS * CC2 * 4);        // 16.8 MB
  size_t oGt    = alloc((size_t)BSZ * KVD * CC2 * 2);   // 14.7 MB  Gt[b][c][e]
  size_t oMsum  = alloc((size_t)BSZ * CC2 * KVD * 2);   // 14.7 MB  Msum[b][c2][c]
  size_t oWOT   = alloc((size_t)CC2 * CC2 * 2);
  size_t oF1T   = alloc((size_t)FFD * CC2 * 2);
  size_t oF2T   = alloc((size_t)CC2 * FFD * 2);
  size_t oSTATS = alloc(64 * 4);
  // scratch region (~43 MB), phase-aliased
  size_t oSCR   = alloc(0);
  // phase A: CXLNT (8.4) + EMBLNT (29.4)
  size_t oCXLNT  = alloc((size_t)BSZ * CC2 * NTOK * 2);
  size_t oEMBLNT = alloc((size_t)BSZ * KVD * NTOK * 2);
  (void)ws_size; (void)in_sizes; (void)n_in; (void)out_size;

  bf16_t* EMBLN  = (bf16_t*)(ws + oEMBLN);
  bf16_t* CXLN   = (bf16_t*)(ws + oCXLN);
  float*  CX2    = (float*)(ws + oCX2);
  bf16_t* Gt     = (bf16_t*)(ws + oGt);
  bf16_t* Msum   = (bf16_t*)(ws + oMsum);
  bf16_t* WOT    = (bf16_t*)(ws + oWOT);
  bf16_t* F1T    = (bf16_t*)(ws + oF1T);
  bf16_t* F2T    = (bf16_t*)(ws + oF2T);
  float*  STATS  = (float*)(ws + oSTATS);
  bf16_t* CXLNT  = (bf16_t*)(ws + oCXLNT);
  bf16_t* EMBLNT = (bf16_t*)(ws + oEMBLNT);
  // phase B (head loop) aliases scratch: WqT .5 + WkT 6.4 + WvB 6.4 + T1 14.7 + SC 14.7
  char* scr = ws + oSCR;
  bf16_t* WqT = (bf16_t*)(scr);
  bf16_t* WkT = (bf16_t*)(scr + ((size_t)CC2 * CC2 * 2 + 255 & ~(size_t)255));
  bf16_t* WvB = (bf16_t*)((char*)WkT + ((size_t)KVD * KVD * 2 + 255 & ~(size_t)255));
  bf16_t* T1  = (bf16_t*)((char*)WvB + ((size_t)KVD * KVD * 2 + 255 & ~(size_t)255));
  bf16_t* SC  = (bf16_t*)((char*)T1 + ((size_t)BSZ * CC2 * KVD * 2 + 255 & ~(size_t)255));
  // phase C aliases scratch: CTX (8.4) then FFNH (33.5)
  bf16_t* CTX  = (bf16_t*)(scr);
  bf16_t* FFNH = (bf16_t*)(scr + (((size_t)ROWS * CC2 * 2 + 255) & ~(size_t)255));
  bf16_t* X2LN = CXLN;  // ffn-LN aliases cxln (dead after Gt)

  // stats zero + global weight transpose-converts
  zstats_k<<<1, 64, 0, stream>>>(STATS);
  tconv_k<<<dim3(16, 16), 256, 0, stream>>>(Wout, WOT, 512, 512);
  tconv_k<<<dim3(64, 16), 256, 0, stream>>>(fc1_w, F1T, 512, 2048);
  tconv_k<<<dim3(16, 64), 256, 0, stream>>>(fc2_w, F2T, 2048, 512);

  // fused layernorms -> bf16 activations
  ln_concat_k<<<8192, 256, 0, stream>>>(emb1, emb2, emb3, ln1_g, ln1_b,
                                        lnall_g, lnall_b, CXLN, EMBLN);

  // token-major transposes (once), then G^T[b][c][e] = sum_n E[n][c] CXLN[n][e]
  tconv_bf_k<<<dim3(16, 32, 8), 256, 0, stream>>>(CXLN, CXLNT, 1024, 512);
  tconv_bf_k<<<dim3(56, 32, 8), 256, 0, stream>>>(EMBLN, EMBLNT, 1024, 1792);
  gemm_ab<<<dim3(14, 4, 8), 256, 0, stream>>>(EMBLNT, (long)KVD * NTOK,
                                              CXLNT, (long)CC2 * NTOK,
                                              Gt, (long)KVD * CC2, NTOK, CC2);

  // attention head loop: S = WqT·Gt^T·WkT^T, P = softmax(instnorm(S)), Msum += 0.25·P·Wv^T
  for (int h = 0; h < NH; ++h) {
    tconv_k<<<dim3(16, 16), 256, 0, stream>>>(Wq + (long)h * CC2 * CC2, WqT, 512, 512);
    tconv_k<<<dim3(56, 56), 256, 0, stream>>>(Wk + (long)h * KVD * KVD, WkT, 1792, 1792);
    cast_k<<<3136, 256, 0, stream>>>(Wv + (long)h * KVD * KVD, WvB, (long)KVD * KVD);

    // T1[b][c2][c] = sum_e WqT[c2][e] Gt[b][c][e]
    gemm_ab<<<dim3(4, 14, 8), 256, 0, stream>>>(WqT, 0L,
                                                Gt, (long)KVD * CC2,
                                                T1, (long)CC2 * KVD, CC2, KVD);
    // S + instance-norm stats; softmax
    gemm_scores<<<dim3(4, 14, 8), 256, 0, stream>>>(T1, WkT, SC, STATS + h * 16);
    softmax_k<<<4096, 256, 0, stream>>>(SC, STATS + h * 16);
    // Msum += 0.25 * P·Wv^T
    gemm_macc<<<dim3(4, 14, 8), 256, 0, stream>>>(SC, WvB, Msum, h == 0 ? 1 : 0);
  }

  // ctx[b][n][c2] = sum_c E[n][c] Msum[b][c2][c]
  gemm_ab<<<dim3(8, 4, 8), 256, 0, stream>>>(EMBLN, (long)NTOK * KVD,
                                             Msum, (long)CC2 * KVD,
                                             CTX, (long)NTOK * CC2, KVD, CC2);

  // o-proj + residual
  gemm_resid<<<dim3(64, 4), 256, 0, stream>>>(CTX, WOT, emb2, CX2);

  // FFN
  ln2_k<<<8192, 256, 0, stream>>>(CX2, lnffn_g, lnffn_b, X2LN);
  gemm_gelu<<<dim3(64, 16), 256, 0, stream>>>(X2LN, F1T, fc1_b, FFNH);
  gemm_out<<<dim3(64, 4), 256, 0, stream>>>(FFNH, F2T, fc2_b, CX2, out);
}

// Round 4
// 884.809 us; speedup vs baseline: 1.7580x; 1.0697x over previous
//
#include <hip/hip_runtime.h>
#include <cstdint>
#include <cmath>

typedef __bf16 bf16_t;
typedef __attribute__((ext_vector_type(8))) __bf16 bf16x8;
typedef __attribute__((ext_vector_type(4))) float f32x4;

#define AS_G(x) ((__attribute__((address_space(1))) void*)(x))
#define AS_L(x) ((__attribute__((address_space(3))) void*)(x))

#define BK 64

// problem constants
#define BSZ 8
#define NTOK 1024
#define CC2 512
#define KVD 1792
#define NH 4
#define FFD 2048
#define ROWS 8192  // B*N

// ---------------- GEMM core (128x128 tile, BK=64, XOR-swizzled LDS, 16x16x32 MFMA) ---------
// LDS layout: lds[r][slot] holds global[r][slot ^ (r&7)] in 16B chunks (8 bf16).
// Swizzle applied on the global fetch side (legal: only LDS side of global_load_lds is
// constrained to wave-uniform-base+lane*16). Reader XORs again -> identity; quad lanes
// spread over all 32 banks (2-way, free) instead of 16-way conflict at 128B row stride.

__device__ __forceinline__ void stage_pair(const bf16_t* __restrict__ A,
                                           const bf16_t* __restrict__ B,
                                           int ld, bf16_t* ldsA, bf16_t* ldsB, int tid)
{
#pragma unroll
  for (int it = 0; it < 4; ++it) {
    int chunk = it * 256 + tid;          // 0..1023
    int r = chunk >> 3;                  // 0..127
    int s = chunk & 7;                   // lds slot (16B chunk)
    int cg = ((s ^ (r & 7)) << 3);       // swizzled global column (elements)
    __builtin_amdgcn_global_load_lds(AS_G(A + (long)r * ld + cg),
                                     AS_L(ldsA + chunk * 8), 16, 0, 0);
    __builtin_amdgcn_global_load_lds(AS_G(B + (long)r * ld + cg),
                                     AS_L(ldsB + chunk * 8), 16, 0, 0);
  }
}

__device__ __forceinline__ void mfma_step(const bf16_t* ldsA, const bf16_t* ldsB,
                                          f32x4 acc[4][4], int wr, int wc, int lane, int kc)
{
  // kc = base 16B-chunk index (0 or 4) covering elements kc*8 .. kc*8+31
  const int quad = lane >> 4, l16 = lane & 15;
  bf16x8 a[4], b[4];
#pragma unroll
  for (int i = 0; i < 4; ++i) {
    int r = wr * 64 + i * 16 + l16;
    int slot = (kc + quad) ^ (r & 7);
    a[i] = *(const bf16x8*)(ldsA + r * BK + slot * 8);
  }
#pragma unroll
  for (int j = 0; j < 4; ++j) {
    int r = wc * 64 + j * 16 + l16;
    int slot = (kc + quad) ^ (r & 7);
    b[j] = *(const bf16x8*)(ldsB + r * BK + slot * 8);
  }
#pragma unroll
  for (int i = 0; i < 4; ++i)
#pragma unroll
    for (int j = 0; j < 4; ++j)
      acc[i][j] = __builtin_amdgcn_mfma_f32_16x16x32_bf16(a[i], b[j], acc[i][j], 0, 0, 0);
}

#define GEMM_PROLOG() \
  __shared__ __align__(16) bf16_t ldsA[128 * BK]; \
  __shared__ __align__(16) bf16_t ldsB[128 * BK]; \
  const int tid = threadIdx.x; \
  const int wave = tid >> 6, lane = tid & 63; \
  const int wr = wave >> 1, wc = wave & 1; \
  f32x4 acc[4][4] = {};

#define GEMM_LOOP(Aptr, Bptr, Kdim) \
  for (int k0 = 0; k0 < (Kdim); k0 += BK) { \
    stage_pair((Aptr) + k0, (Bptr) + k0, (Kdim), ldsA, ldsB, tid); \
    __syncthreads(); \
    mfma_step(ldsA, ldsB, acc, wr, wc, lane, 0); \
    mfma_step(ldsA, ldsB, acc, wr, wc, lane, 4); \
    __syncthreads(); \
  }

template <typename F>
__device__ __forceinline__ void epilogue_apply(f32x4 acc[4][4], int wr, int wc, int lane, F f)
{
  const int quad = lane >> 4, l16 = lane & 15;
#pragma unroll
  for (int i = 0; i < 4; ++i)
#pragma unroll
    for (int j = 0; j < 4; ++j)
#pragma unroll
      for (int r = 0; r < 4; ++r)
        f(wr * 64 + i * 16 + quad * 4 + r, wc * 64 + j * 16 + l16, acc[i][j][r]);
}

// ---------------- small kernels -----------------------------------------------------------

__global__ void zstats_k(float* s)
{
  if (threadIdx.x < 64) s[threadIdx.x] = 0.f;
}

// transpose-convert: in f32 [Z][R][C] -> out bf16 [Z][C][R]
__global__ __launch_bounds__(256) void tconv_k(const float* __restrict__ in,
                                               bf16_t* __restrict__ out, int R, int Cc)
{
  __shared__ float tile[32][33];
  const long base = (long)blockIdx.z * R * Cc;
  const int c0 = blockIdx.x * 32, r0 = blockIdx.y * 32;
  const int tx = threadIdx.x & 31, ty = threadIdx.x >> 5;
#pragma unroll
  for (int i = 0; i < 4; ++i)
    tile[ty + i * 8][tx] = in[base + (long)(r0 + ty + i * 8) * Cc + c0 + tx];
  __syncthreads();
#pragma unroll
  for (int i = 0; i < 4; ++i)
    out[base + (long)(c0 + ty + i * 8) * R + r0 + tx] = (bf16_t)tile[tx][ty + i * 8];
}

// transpose bf16 [Z][R][C] -> bf16 [Z][C][R]
__global__ __launch_bounds__(256) void tconv_bf_k(const bf16_t* __restrict__ in,
                                                  bf16_t* __restrict__ out, int R, int Cc)
{
  __shared__ float tile[32][33];
  const long base = (long)blockIdx.z * R * Cc;
  const int c0 = blockIdx.x * 32, r0 = blockIdx.y * 32;
  const int tx = threadIdx.x & 31, ty = threadIdx.x >> 5;
#pragma unroll
  for (int i = 0; i < 4; ++i)
    tile[ty + i * 8][tx] = (float)in[base + (long)(r0 + ty + i * 8) * Cc + c0 + tx];
  __syncthreads();
#pragma unroll
  for (int i = 0; i < 4; ++i)
    out[base + (long)(c0 + ty + i * 8) * R + r0 + tx] = (bf16_t)tile[tx][ty + i * 8];
}

// f32 -> bf16 cast (no transpose), n multiple of 1024
__global__ __launch_bounds__(256) void cast_k(const float* __restrict__ in,
                                              bf16_t* __restrict__ out, long n)
{
  long i = ((long)blockIdx.x * 256 + threadIdx.x) * 4;
  if (i + 3 < n) {
    float4 v = *(const float4*)(in + i);
    out[i] = (bf16_t)v.x; out[i + 1] = (bf16_t)v.y;
    out[i + 2] = (bf16_t)v.z; out[i + 3] = (bf16_t)v.w;
  }
}

// fused LN(emb2) and LN(concat(emb1,emb2,emb3)), bf16 outputs
__global__ __launch_bounds__(256) void ln_concat_k(const float* __restrict__ e1,
                                                   const float* __restrict__ e2,
                                                   const float* __restrict__ e3,
                                                   const float* __restrict__ g1,
                                                   const float* __restrict__ b1,
                                                   const float* __restrict__ ga,
                                                   const float* __restrict__ ba,
                                                   bf16_t* __restrict__ cxln,
                                                   bf16_t* __restrict__ embln)
{
  const long row = blockIdx.x;
  const float* p1 = e1 + row * 256;
  const float* p2 = e2 + row * 512;
  const float* p3 = e3 + row * 1024;
  const int t = threadIdx.x;
  float vals[7];
  float sa = 0.f, qa = 0.f;
#pragma unroll
  for (int i = 0; i < 7; ++i) {
    int idx = t + i * 256;
    float x = (idx < 256) ? p1[idx] : (idx < 768 ? p2[idx - 256] : p3[idx - 768]);
    vals[i] = x;
    sa += x; qa += x * x;
  }
  float s2 = vals[1] + vals[2];
  float q2 = vals[1] * vals[1] + vals[2] * vals[2];
  for (int off = 32; off; off >>= 1) {
    sa += __shfl_down(sa, off, 64); qa += __shfl_down(qa, off, 64);
    s2 += __shfl_down(s2, off, 64); q2 += __shfl_down(q2, off, 64);
  }
  __shared__ float red[4][4];
  const int wave = t >> 6, lane = t & 63;
  if (lane == 0) { red[0][wave] = sa; red[1][wave] = qa; red[2][wave] = s2; red[3][wave] = q2; }
  __syncthreads();
  float SA = red[0][0] + red[0][1] + red[0][2] + red[0][3];
  float QA = red[1][0] + red[1][1] + red[1][2] + red[1][3];
  float S2 = red[2][0] + red[2][1] + red[2][2] + red[2][3];
  float Q2 = red[3][0] + red[3][1] + red[3][2] + red[3][3];
  float ma = SA * (1.f / 1792.f);
  float va = QA * (1.f / 1792.f) - ma * ma;
  float rsa = rsqrtf(va + 1e-6f);
  float m2 = S2 * (1.f / 512.f);
  float v2 = Q2 * (1.f / 512.f) - m2 * m2;
  float rs2 = rsqrtf(v2 + 1e-6f);
#pragma unroll
  for (int i = 0; i < 7; ++i) {
    int idx = t + i * 256;
    embln[row * 1792 + idx] = (bf16_t)((vals[i] - ma) * rsa * ga[idx] + ba[idx]);
  }
  cxln[row * 512 + t]       = (bf16_t)((vals[1] - m2) * rs2 * g1[t] + b1[t]);
  cxln[row * 512 + t + 256] = (bf16_t)((vals[2] - m2) * rs2 * g1[t + 256] + b1[t + 256]);
}

// plain LN over 512 (fp32 in -> bf16 out)
__global__ __launch_bounds__(256) void ln2_k(const float* __restrict__ X,
                                             const float* __restrict__ g,
                                             const float* __restrict__ bb,
                                             bf16_t* __restrict__ Y)
{
  const long row = blockIdx.x;
  const float* p = X + row * 512;
  const int t = threadIdx.x;
  float x0 = p[t], x1 = p[t + 256];
  float s = x0 + x1, q = x0 * x0 + x1 * x1;
  for (int off = 32; off; off >>= 1) {
    s += __shfl_down(s, off, 64); q += __shfl_down(q, off, 64);
  }
  __shared__ float red[2][4];
  const int wave = t >> 6, lane = t & 63;
  if (lane == 0) { red[0][wave] = s; red[1][wave] = q; }
  __syncthreads();
  float S = red[0][0] + red[0][1] + red[0][2] + red[0][3];
  float Q = red[1][0] + red[1][1] + red[1][2] + red[1][3];
  float m = S * (1.f / 512.f);
  float v = Q * (1.f / 512.f) - m * m;
  float rs = rsqrtf(v + 1e-6f);
  Y[row * 512 + t]       = (bf16_t)((x0 - m) * rs * g[t] + bb[t]);
  Y[row * 512 + t + 256] = (bf16_t)((x1 - m) * rs * g[t + 256] + bb[t + 256]);
}

// softmax over last dim (1792), with instance-norm scale (shift-invariant), in place on bf16
// per head-pair: grid = 16*512 rows; stats has 16 (z) entries of {sum, sumsq}
__global__ __launch_bounds__(256) void softmax_k(bf16_t* __restrict__ SC,
                                                 const float* __restrict__ stats)
{
  const long rowid = blockIdx.x;          // z*512 + c
  const int z = (int)(rowid >> 9);
  const float inv_cnt = 1.f / (512.f * 1792.f);
  float m = stats[2 * z] * inv_cnt;
  float var = stats[2 * z + 1] * inv_cnt - m * m;
  float rs = rsqrtf(var + 1e-5f);
  bf16_t* rowp = SC + rowid * 1792;
  const int t = threadIdx.x;
  float v[7];
  float mx = -1e30f;
#pragma unroll
  for (int i = 0; i < 7; ++i) {
    v[i] = (float)rowp[t + i * 256] * rs;
    mx = fmaxf(mx, v[i]);
  }
  for (int off = 32; off; off >>= 1) mx = fmaxf(mx, __shfl_down(mx, off, 64));
  __shared__ float red[8];
  const int wave = t >> 6, lane = t & 63;
  if (lane == 0) red[wave] = mx;
  __syncthreads();
  mx = fmaxf(fmaxf(red[0], red[1]), fmaxf(red[2], red[3]));
  float sum = 0.f;
#pragma unroll
  for (int i = 0; i < 7; ++i) { v[i] = __expf(v[i] - mx); sum += v[i]; }
  for (int off = 32; off; off >>= 1) sum += __shfl_down(sum, off, 64);
  if (lane == 0) red[4 + wave] = sum;
  __syncthreads();
  float inv = 1.f / (red[4] + red[5] + red[6] + red[7]);
#pragma unroll
  for (int i = 0; i < 7; ++i) rowp[t + i * 256] = (bf16_t)(v[i] * inv);
}

// ---------------- GEMM kernels ------------------------------------------------------------
// head-pair batching: blockIdx.z = z in [0,16), hh = z>>3 (head within pair), b = z&7

// generic: C[z][m][n] = sum_k A[z][m][k] B[z][n][k] (stride 0 = shared operand)
__global__ __launch_bounds__(256) void gemm_ab(const bf16_t* __restrict__ A, long astride,
                                               const bf16_t* __restrict__ B, long bstride,
                                               bf16_t* __restrict__ C, long cstride,
                                               int K, int ldc)
{
  const int z = blockIdx.z;
  GEMM_PROLOG();
  const bf16_t* Ap = A + z * astride + (long)blockIdx.x * 128 * K;
  const bf16_t* Bp = B + z * bstride + (long)blockIdx.y * 128 * K;
  GEMM_LOOP(Ap, Bp, K);
  bf16_t* Cb = C + (long)z * cstride;
  const int rbase = blockIdx.x * 128, cbase = blockIdx.y * 128;
  epilogue_apply(acc, wr, wc, lane, [&](int rr, int cc, float v) {
    Cb[(long)(rbase + rr) * ldc + cbase + cc] = (bf16_t)v;
  });
}

// T1[z][c2][c] = sum_e WqT[hh][c2][e] Gt[b][c][e]
__global__ __launch_bounds__(256) void gemm_t1(const bf16_t* __restrict__ WqT,
                                               const bf16_t* __restrict__ Gt,
                                               bf16_t* __restrict__ T1)
{
  const int z = blockIdx.z, hh = z >> 3, b = z & 7;
  GEMM_PROLOG();
  const bf16_t* Ap = WqT + (long)hh * CC2 * CC2 + (long)blockIdx.x * 128 * CC2;
  const bf16_t* Bp = Gt + (long)b * KVD * CC2 + (long)blockIdx.y * 128 * CC2;
  GEMM_LOOP(Ap, Bp, CC2);
  bf16_t* Cb = T1 + (long)z * CC2 * KVD;
  const int rbase = blockIdx.x * 128, cbase = blockIdx.y * 128;
  epilogue_apply(acc, wr, wc, lane, [&](int rr, int cc, float v) {
    Cb[(long)(rbase + rr) * KVD + cbase + cc] = (bf16_t)v;
  });
}

// scores: SC[z][c2][d] = sum_c T1[z][c2][c] WkT[hh][d][c] / sqrt(KV); + per-z sum/sumsq
__global__ __launch_bounds__(256) void gemm_scores(const bf16_t* __restrict__ T1,
                                                   const bf16_t* __restrict__ WkT,
                                                   bf16_t* __restrict__ SC,
                                                   float* __restrict__ stats)
{
  const int z = blockIdx.z, hh = z >> 3;
  GEMM_PROLOG();
  const bf16_t* Ap = T1 + (long)z * CC2 * KVD + (long)blockIdx.x * 128 * KVD;
  const bf16_t* Bp = WkT + (long)hh * KVD * KVD + (long)blockIdx.y * 128 * KVD;
  GEMM_LOOP(Ap, Bp, KVD);
  const float scale = 0.02362277854f;  // 1/sqrt(1792)
  bf16_t* Cb = SC + (long)z * CC2 * KVD;
  const int rbase = blockIdx.x * 128, cbase = blockIdx.y * 128;
  float s = 0.f, q = 0.f;
  epilogue_apply(acc, wr, wc, lane, [&](int rr, int cc, float v) {
    v *= scale;
    Cb[(long)(rbase + rr) * KVD + cbase + cc] = (bf16_t)v;
    s += v; q += v * v;
  });
  for (int off = 32; off; off >>= 1) { s += __shfl_down(s, off, 64); q += __shfl_down(q, off, 64); }
  __shared__ float red[8];
  if (lane == 0) { red[wave] = s; red[4 + wave] = q; }
  __syncthreads();
  if (tid == 0) {
    atomicAdd(&stats[2 * z],     red[0] + red[1] + red[2] + red[3]);
    atomicAdd(&stats[2 * z + 1], red[4] + red[5] + red[6] + red[7]);
  }
}

// Msum[z][c2][c] (+)= 0.25 * sum_d P[z][c2][d] WvB[hh][c][d]  (per-pair accumulate)
__global__ __launch_bounds__(256) void gemm_macc(const bf16_t* __restrict__ P,
                                                 const bf16_t* __restrict__ WvB,
                                                 bf16_t* __restrict__ M, int first)
{
  const int z = blockIdx.z, hh = z >> 3;
  GEMM_PROLOG();
  const bf16_t* Ap = P + (long)z * CC2 * KVD + (long)blockIdx.x * 128 * KVD;
  const bf16_t* Bp = WvB + (long)hh * KVD * KVD + (long)blockIdx.y * 128 * KVD;
  GEMM_LOOP(Ap, Bp, KVD);
  bf16_t* Cb = M + (long)z * CC2 * KVD;
  const int rbase = blockIdx.x * 128, cbase = blockIdx.y * 128;
  epilogue_apply(acc, wr, wc, lane, [&](int rr, int cc, float v) {
    long idx = (long)(rbase + rr) * KVD + cbase + cc;
    float prev = first ? 0.f : (float)Cb[idx];
    Cb[idx] = (bf16_t)(prev + v * 0.25f);
  });
}

// ctx[b][n][c2] = sum_c E[b][n][c] (Msum[b] + Msum[8+b])[c2][c]
__global__ __launch_bounds__(256) void gemm_ctx(const bf16_t* __restrict__ E,
                                                const bf16_t* __restrict__ Msum,
                                                bf16_t* __restrict__ CTX)
{
  const int b = blockIdx.z;
  GEMM_PROLOG();
  const bf16_t* Ap = E + (long)b * NTOK * KVD + (long)blockIdx.x * 128 * KVD;
  const bf16_t* Bp0 = Msum + (long)b * CC2 * KVD + (long)blockIdx.y * 128 * KVD;
  const bf16_t* Bp1 = Msum + (long)(8 + b) * CC2 * KVD + (long)blockIdx.y * 128 * KVD;
  GEMM_LOOP(Ap, Bp0, KVD);
  GEMM_LOOP(Ap, Bp1, KVD);
  bf16_t* Cb = CTX + (long)b * NTOK * CC2;
  const int rbase = blockIdx.x * 128, cbase = blockIdx.y * 128;
  epilogue_apply(acc, wr, wc, lane, [&](int rr, int cc, float v) {
    Cb[(long)(rbase + rr) * CC2 + cbase + cc] = (bf16_t)v;
  });
}

// o-proj + residual: CX2 = CTX@WOT^T + emb2 (fp32 out)
__global__ __launch_bounds__(256) void gemm_resid(const bf16_t* __restrict__ A,
                                                  const bf16_t* __restrict__ B,
                                                  const float* __restrict__ emb2,
                                                  float* __restrict__ CX2)
{
  GEMM_PROLOG();
  const bf16_t* Ap = A + (long)blockIdx.x * 128 * CC2;
  const bf16_t* Bp = B + (long)blockIdx.y * 128 * CC2;
  GEMM_LOOP(Ap, Bp, CC2);
  const int rbase = blockIdx.x * 128, cbase = blockIdx.y * 128;
  epilogue_apply(acc, wr, wc, lane, [&](int rr, int cc, float v) {
    long idx = (long)(rbase + rr) * CC2 + cbase + cc;
    CX2[idx] = v + emb2[idx];
  });
}

// fc1 + bias + exact gelu -> bf16
__global__ __launch_bounds__(256) void gemm_gelu(const bf16_t* __restrict__ A,
                                                 const bf16_t* __restrict__ B,
                                                 const float* __restrict__ bias,
                                                 bf16_t* __restrict__ H)
{
  GEMM_PROLOG();
  const bf16_t* Ap = A + (long)blockIdx.x * 128 * CC2;
  const bf16_t* Bp = B + (long)blockIdx.y * 128 * CC2;
  GEMM_LOOP(Ap, Bp, CC2);
  const int rbase = blockIdx.x * 128, cbase = blockIdx.y * 128;
  epilogue_apply(acc, wr, wc, lane, [&](int rr, int cc, float v) {
    float x = v + bias[cbase + cc];
    float g = 0.5f * x * (1.0f + erff(x * 0.70710678118f));
    H[(long)(rbase + rr) * FFD + cbase + cc] = (bf16_t)g;
  });
}

// fc2 + bias + residual -> fp32 out
__global__ __launch_bounds__(256) void gemm_out(const bf16_t* __restrict__ A,
                                                const bf16_t* __restrict__ B,
                                                const float* __restrict__ bias,
                                                const float* __restrict__ CX2,
                                                float* __restrict__ OUT)
{
  GEMM_PROLOG();
  const bf16_t* Ap = A + (long)blockIdx.x * 128 * FFD;
  const bf16_t* Bp = B + (long)blockIdx.y * 128 * FFD;
  GEMM_LOOP(Ap, Bp, FFD);
  const int rbase = blockIdx.x * 128, cbase = blockIdx.y * 128;
  epilogue_apply(acc, wr, wc, lane, [&](int rr, int cc, float v) {
    long idx = (long)(rbase + rr) * CC2 + cbase + cc;
    OUT[idx] = v + bias[cbase + cc] + CX2[idx];
  });
}

// ---------------- host launcher -----------------------------------------------------------

extern "C" void kernel_launch(void* const* d_in, const int* in_sizes, int n_in,
                              void* d_out, int out_size, void* d_ws, size_t ws_size,
                              hipStream_t stream)
{
  const float* emb1   = (const float*)d_in[0];
  const float* emb2   = (const float*)d_in[1];
  const float* emb3   = (const float*)d_in[2];
  const float* Wq     = (const float*)d_in[3];
  const float* Wk     = (const float*)d_in[4];
  const float* Wv     = (const float*)d_in[5];
  const float* Wout   = (const float*)d_in[6];
  const float* ln1_g  = (const float*)d_in[7];
  const float* ln1_b  = (const float*)d_in[8];
  const float* lnall_g = (const float*)d_in[9];
  const float* lnall_b = (const float*)d_in[10];
  const float* lnffn_g = (const float*)d_in[11];
  const float* lnffn_b = (const float*)d_in[12];
  const float* fc1_w  = (const float*)d_in[13];
  const float* fc1_b  = (const float*)d_in[14];
  const float* fc2_w  = (const float*)d_in[15];
  const float* fc2_b  = (const float*)d_in[16];
  float* out = (float*)d_out;

  char* ws = (char*)d_ws;
  size_t off = 0;
  auto alloc = [&](size_t bytes) {
    size_t r = off;
    off = (off + bytes + 255) & ~(size_t)255;
    return r;
  };

  // persistent buffers (~99 MiB)
  size_t oEMBLN = alloc((size_t)ROWS * KVD * 2);          // 29.4 MB (until ctx GEMM)
  size_t oCXLN  = alloc((size_t)ROWS * CC2 * 2);          // 8.4 MB; X2LN aliases later
  size_t oCX2   = alloc((size_t)ROWS * CC2 * 4);          // 16.8 MB
  size_t oGt    = alloc((size_t)BSZ * KVD * CC2 * 2);     // 14.7 MB  Gt[b][c][e]
  size_t oMsum  = alloc((size_t)16 * CC2 * KVD * 2);      // 29.4 MB  Msum[hh*8+b][c2][c]
  size_t oWOT   = alloc((size_t)CC2 * CC2 * 2);
  size_t oF1T   = alloc((size_t)FFD * CC2 * 2);
  size_t oF2T   = alloc((size_t)CC2 * FFD * 2);
  size_t oSTATS = alloc(64 * 4);
  // scratch region (~86 MiB), phase-aliased
  size_t oSCR   = alloc(0);
  size_t oCXLNT  = alloc((size_t)BSZ * CC2 * NTOK * 2);   // phase A
  size_t oEMBLNT = alloc((size_t)BSZ * KVD * NTOK * 2);
  (void)ws_size; (void)in_sizes; (void)n_in; (void)out_size;

  bf16_t* EMBLN  = (bf16_t*)(ws + oEMBLN);
  bf16_t* CXLN   = (bf16_t*)(ws + oCXLN);
  float*  CX2    = (float*)(ws + oCX2);
  bf16_t* Gt     = (bf16_t*)(ws + oGt);
  bf16_t* Msum   = (bf16_t*)(ws + oMsum);
  bf16_t* WOT    = (bf16_t*)(ws + oWOT);
  bf16_t* F1T    = (bf16_t*)(ws + oF1T);
  bf16_t* F2T    = (bf16_t*)(ws + oF2T);
  float*  STATS  = (float*)(ws + oSTATS);
  bf16_t* CXLNT  = (bf16_t*)(ws + oCXLNT);
  bf16_t* EMBLNT = (bf16_t*)(ws + oEMBLNT);
  // phase B (head-pair loop) aliases scratch: WqT 1 + WkT 12.25 + WvB 12.25 + T1 28 + SC 28 MiB
  char* scr = ws + oSCR;
  auto rnd = [](size_t v) { return (v + 255) & ~(size_t)255; };
  bf16_t* WqT = (bf16_t*)(scr);
  bf16_t* WkT = (bf16_t*)(scr + rnd((size_t)2 * CC2 * CC2 * 2));
  bf16_t* WvB = (bf16_t*)((char*)WkT + rnd((size_t)2 * KVD * KVD * 2));
  bf16_t* T1  = (bf16_t*)((char*)WvB + rnd((size_t)2 * KVD * KVD * 2));
  bf16_t* SC  = (bf16_t*)((char*)T1 + rnd((size_t)16 * CC2 * KVD * 2));
  // phase C aliases scratch: CTX (8.4) then FFNH (33.5)
  bf16_t* CTX  = (bf16_t*)(scr);
  bf16_t* FFNH = (bf16_t*)(scr + rnd((size_t)ROWS * CC2 * 2));
  bf16_t* X2LN = CXLN;  // ffn-LN aliases cxln (dead after transposes)

  // stats zero + global weight transpose-converts
  zstats_k<<<1, 64, 0, stream>>>(STATS);
  tconv_k<<<dim3(16, 16), 256, 0, stream>>>(Wout, WOT, 512, 512);
  tconv_k<<<dim3(64, 16), 256, 0, stream>>>(fc1_w, F1T, 512, 2048);
  tconv_k<<<dim3(16, 64), 256, 0, stream>>>(fc2_w, F2T, 2048, 512);

  // fused layernorms -> bf16 activations
  ln_concat_k<<<8192, 256, 0, stream>>>(emb1, emb2, emb3, ln1_g, ln1_b,
                                        lnall_g, lnall_b, CXLN, EMBLN);

  // token-major transposes (once), then G^T[b][c][e] = sum_n E[n][c] CXLN[n][e]
  tconv_bf_k<<<dim3(16, 32, 8), 256, 0, stream>>>(CXLN, CXLNT, 1024, 512);
  tconv_bf_k<<<dim3(56, 32, 8), 256, 0, stream>>>(EMBLN, EMBLNT, 1024, 1792);
  gemm_ab<<<dim3(14, 4, 8), 256, 0, stream>>>(EMBLNT, (long)KVD * NTOK,
                                              CXLNT, (long)CC2 * NTOK,
                                              Gt, (long)KVD * CC2, NTOK, CC2);

  // attention, two heads per iteration (z = hh*8 + b, 16 batches per launch)
  for (int g = 0; g < 2; ++g) {
    tconv_k<<<dim3(16, 16, 2), 256, 0, stream>>>(Wq + (long)g * 2 * CC2 * CC2, WqT, 512, 512);
    tconv_k<<<dim3(56, 56, 2), 256, 0, stream>>>(Wk + (long)g * 2 * KVD * KVD, WkT, 1792, 1792);
    cast_k<<<6272, 256, 0, stream>>>(Wv + (long)g * 2 * KVD * KVD, WvB, (long)2 * KVD * KVD);

    gemm_t1<<<dim3(4, 14, 16), 256, 0, stream>>>(WqT, Gt, T1);
    gemm_scores<<<dim3(4, 14, 16), 256, 0, stream>>>(T1, WkT, SC, STATS + g * 32);
    softmax_k<<<8192, 256, 0, stream>>>(SC, STATS + g * 32);
    gemm_macc<<<dim3(4, 14, 16), 256, 0, stream>>>(SC, WvB, Msum, g == 0 ? 1 : 0);
  }

  // ctx[b][n][c2] = E · (Msum[hh=0] + Msum[hh=1])^T
  gemm_ctx<<<dim3(8, 4, 8), 256, 0, stream>>>(EMBLN, Msum, CTX);

  // o-proj + residual
  gemm_resid<<<dim3(64, 4), 256, 0, stream>>>(CTX, WOT, emb2, CX2);

  // FFN
  ln2_k<<<8192, 256, 0, stream>>>(CX2, lnffn_g, lnffn_b, X2LN);
  gemm_gelu<<<dim3(64, 16), 256, 0, stream>>>(X2LN, F1T, fc1_b, FFNH);
  gemm_out<<<dim3(64, 4), 256, 0, stream>>>(FFNH, F2T, fc2_b, CX2, out);
}